// Round 7
// baseline (97.257 us; speedup 1.0000x reference)
//
#include <hip/hip_runtime.h>
#include <math.h>

typedef __attribute__((ext_vector_type(8))) short bf16x8;
typedef __attribute__((ext_vector_type(4))) short bf16x4;
typedef __attribute__((ext_vector_type(4))) float f32x4;

__device__ inline ushort f2bf(float f) {
    union { float f; uint u; } v; v.f = f;
    uint u = v.u;
    return (ushort)((u + 0x7fff + ((u >> 16) & 1)) >> 16);   // RNE
}
__device__ inline float bf2f(ushort u) {
    union { uint u; float f; } v; v.u = ((uint)u) << 16; return v.f;
}

// ---------------------------------------------------------------------------
// MFMA bf16 GEMM, converts inputs on the fly.  (unchanged; passed R3-R6)
// ---------------------------------------------------------------------------
template<int BM, int BN, int WGM, int WGN, int MODE>
__global__ __launch_bounds__(WGM * WGN * 64) void gemm_fused(
    const void* __restrict__ Ap, const float* __restrict__ Bw, int ldb,
    const float* __restrict__ bias,
    void* __restrict__ C0, void* __restrict__ C1, void* __restrict__ C2,
    int K, int N)
{
    constexpr int BK = 32;
    constexpr int NT = WGM * WGN * 64;
    constexpr int WM = BM / (WGM * 16);
    constexpr int WN = BN / (WGN * 16);

    __shared__ ushort As[BM * BK];
    __shared__ ushort Bs[BN * BK];

    const int tid = threadIdx.x;
    const int lane = tid & 63, wid = tid >> 6;
    const int wm = wid / WGN, wn = wid % WGN;
    const int row0 = blockIdx.y * BM, col0 = blockIdx.x * BN;
    const int frow = lane & 15, fg = lane >> 4;

    f32x4 acc[WM][WN] = {};

    for (int k0 = 0; k0 < K; k0 += BK) {
        if constexpr (MODE == 0) {
            #pragma unroll
            for (int ci = tid; ci < BM * 8; ci += NT) {
                int r = ci >> 3, kq = ci & 7, g = kq >> 1;
                float4 v = *(const float4*)((const float*)Ap + (size_t)(row0 + r) * K + k0 + kq * 4);
                bf16x4 o;
                o[0] = (short)f2bf(v.x); o[1] = (short)f2bf(v.y);
                o[2] = (short)f2bf(v.z); o[3] = (short)f2bf(v.w);
                *(bf16x4*)&As[r * 32 + ((g ^ ((r >> 1) & 3)) << 3) + (kq & 1) * 4] = o;
            }
        } else {
            #pragma unroll
            for (int ci = tid; ci < BM * 4; ci += NT) {
                int r = ci >> 2, g = ci & 3;
                bf16x8 v = *(const bf16x8*)((const ushort*)Ap + (size_t)(row0 + r) * K + k0 + g * 8);
                *(bf16x8*)&As[r * 32 + ((g ^ ((r >> 1) & 3)) << 3)] = v;
            }
        }
        #pragma unroll
        for (int ci = tid; ci < BN * 8; ci += NT) {
            int kk = ci & 31, n4 = ci >> 5;
            float4 v = *(const float4*)&Bw[(size_t)(k0 + kk) * ldb + col0 + n4 * 4];
            float vv[4] = {v.x, v.y, v.z, v.w};
            #pragma unroll
            for (int e = 0; e < 4; ++e) {
                int n = n4 * 4 + e;
                Bs[n * 32 + (((kk >> 3) ^ ((n >> 1) & 3)) << 3) + (kk & 7)] = f2bf(vv[e]);
            }
        }
        __syncthreads();

        bf16x8 af[WM], bfr[WN];
        #pragma unroll
        for (int m = 0; m < WM; ++m) {
            int r = (wm * WM + m) * 16 + frow;
            af[m] = *(const bf16x8*)&As[r * 32 + ((fg ^ ((r >> 1) & 3)) << 3)];
        }
        #pragma unroll
        for (int n = 0; n < WN; ++n) {
            int r = (wn * WN + n) * 16 + frow;
            bfr[n] = *(const bf16x8*)&Bs[r * 32 + ((fg ^ ((r >> 1) & 3)) << 3)];
        }
        #pragma unroll
        for (int m = 0; m < WM; ++m)
            #pragma unroll
            for (int n = 0; n < WN; ++n)
                acc[m][n] = __builtin_amdgcn_mfma_f32_16x16x32_bf16(
                    af[m], bfr[n], acc[m][n], 0, 0, 0);
        __syncthreads();
    }

    #pragma unroll
    for (int n = 0; n < WN; ++n) {
        int gcol = col0 + (wn * WN + n) * 16 + frow;
        float bv = bias[gcol];
        if constexpr (MODE == 0) {
            int b = gcol >> 8, c = gcol & 255;
            ushort* dst = (b == 0) ? (ushort*)C0 : (b == 1) ? (ushort*)C1 : (ushort*)C2;
            #pragma unroll
            for (int m = 0; m < WM; ++m) {
                int grow0 = row0 + (wm * WM + m) * 16 + fg * 4;
                #pragma unroll
                for (int r = 0; r < 4; ++r)
                    dst[(size_t)(grow0 + r) * 256 + c] = f2bf(acc[m][n][r] + bv);
            }
        } else {
            float* dst = (float*)C0;
            #pragma unroll
            for (int m = 0; m < WM; ++m) {
                int grow0 = row0 + (wm * WM + m) * 16 + fg * 4;
                #pragma unroll
                for (int r = 0; r < 4; ++r)
                    dst[(size_t)(grow0 + r) * N + gcol] = acc[m][n][r] + bv;
            }
        }
    }
}

// ---------------------------------------------------------------------------
// Pipelined wave-autonomous relational attention. Grid 1024; block handles
// 4 consecutive items (same bt). Per wave (owns cols [w*64,w*64+64)):
//   - bias slab for item n+1 prefetched into 8xfloat4 regs DURING item n's
//     compute (T14 issue-early/write-late) -> HBM loads always in flight
//   - K fragments register-resident across all 4 items (bt fixed)
//   - no __syncthreads anywhere (wave-private LDS slab, lockstep wave)
// LDS chunk swizzle: 16B chunk cc of row j at slot cc^(j&7).
// ---------------------------------------------------------------------------
__global__ __launch_bounds__(256, 4) void relattn_kernel(
    const ushort* __restrict__ qb, const ushort* __restrict__ kb,
    const ushort* __restrict__ vb, const float* __restrict__ bias,
    const int* __restrict__ mask, ushort* __restrict__ attn_out)
{
    __shared__ ushort slab[4][32 * 64];   // per-wave bf16 col-slab, 4 KB each

    const int b = blockIdx.x;             // 0..1023
    const int item0 = b << 2;             // first (bt,i) item
    const int bt = item0 >> 5;            // constant for all 4 items (4 | 32)
    const int tid = threadIdx.x;
    const int w = tid >> 6, L = tid & 63;
    const int hw = L >> 5;                // which of the wave's two heads
    const int h = 2 * w + hw;
    const int jd = L & 31;                // j in scores, d in PV

    ushort* sl = slab[w];
    const int srow = L >> 4;              // stage row-within-group 0..3
    const int sc4 = L & 15;               // stage float4-col 0..15

    const bool alive = (mask[bt * 32 + jd] != 0);

    // ---- K fragments: load once, reuse for all 4 items ----
    const ushort* krow = kb + (size_t)(bt * 32 + jd) * 256 + h * 32;
    bf16x8 k8[4];
    #pragma unroll
    for (int t = 0; t < 4; ++t) k8[t] = *(const bf16x8*)(krow + t * 8);

    const ushort* vcol = vb + (size_t)bt * 8192 + w * 64 + L;
    const float* bbase = bias + (size_t)item0 * 8192 + w * 64;

    // ---- prologue: prefetch item0 slab (16B/lane coalesced) ----
    float4 pref[8];
    #pragma unroll
    for (int g = 0; g < 8; ++g)
        pref[g] = *(const float4*)(bbase + (size_t)(g * 4 + srow) * 256 + sc4 * 4);

    auto write_slab = [&]() {
        #pragma unroll
        for (int g = 0; g < 8; ++g) {
            int j = g * 4 + srow;
            int cc = sc4 >> 1, half = sc4 & 1;
            bf16x4 o;
            o[0] = (short)f2bf(pref[g].x); o[1] = (short)f2bf(pref[g].y);
            o[2] = (short)f2bf(pref[g].z); o[3] = (short)f2bf(pref[g].w);
            *(bf16x4*)&sl[j * 64 + ((cc ^ (j & 7)) << 3) + half * 4] = o;
        }
    };
    write_slab();

    for (int it = 0; it < 4; ++it) {
        const int blk = item0 + it;

        // ---- issue next item's bias loads (stay in flight under compute) ----
        if (it < 3) {
            const float* nb = bbase + (size_t)(it + 1) * 8192;
            #pragma unroll
            for (int g = 0; g < 8; ++g)
                pref[g] = *(const float4*)(nb + (size_t)(g * 4 + srow) * 256 + sc4 * 4);
        }

        // ---- scores: thread (h, j=jd) ----
        const ushort* qrow = qb + (size_t)blk * 256 + h * 32;
        float s = 0.f;
        #pragma unroll
        for (int t = 0; t < 4; ++t) {
            bf16x8 q8 = *(const bf16x8*)(qrow + t * 8);
            int cc = hw * 4 + t;
            bf16x8 b8 = *(const bf16x8*)&sl[jd * 64 + ((cc ^ (jd & 7)) << 3)];
            #pragma unroll
            for (int e = 0; e < 8; ++e)
                s += bf2f((ushort)q8[e]) * (bf2f((ushort)k8[t][e]) + bf2f((ushort)b8[e]));
        }
        s *= 0.17677669529663687f;  // 1/sqrt(32)
        s = alive ? s : -__builtin_inff();

        // softmax within the 32-lane j-group
        float m = s;
        #pragma unroll
        for (int off = 16; off; off >>= 1) m = fmaxf(m, __shfl_xor(m, off));
        const bool dead = (m == -__builtin_inff());
        float p = alive ? __expf(s - m) : 0.f;
        float l = p;
        #pragma unroll
        for (int off = 16; off; off >>= 1) l += __shfl_xor(l, off);
        float pn = dead ? 0.f : p / l;

        // ---- PV: thread (h, d); p via shfl from same half-wave ----
        const int half32 = L & 32;
        float o0 = 0.f, o1 = 0.f, o2 = 0.f, o3 = 0.f;
        #pragma unroll
        for (int jq = 0; jq < 8; ++jq) {
            int j0 = jq * 4;
            float pa = __shfl(pn, half32 | (j0 + 0));
            float pb = __shfl(pn, half32 | (j0 + 1));
            float pc = __shfl(pn, half32 | (j0 + 2));
            float pd = __shfl(pn, half32 | (j0 + 3));
            float va = bf2f(vcol[(size_t)(j0 + 0) * 256]);
            float vbv = bf2f(vcol[(size_t)(j0 + 1) * 256]);
            float vc = bf2f(vcol[(size_t)(j0 + 2) * 256]);
            float vd = bf2f(vcol[(size_t)(j0 + 3) * 256]);
            float ba = bf2f(sl[(j0 + 0) * 64 + ((((L >> 3) ^ ((j0 + 0) & 7)) << 3) | (L & 7))]);
            float bb = bf2f(sl[(j0 + 1) * 64 + ((((L >> 3) ^ ((j0 + 1) & 7)) << 3) | (L & 7))]);
            float bc = bf2f(sl[(j0 + 2) * 64 + ((((L >> 3) ^ ((j0 + 2) & 7)) << 3) | (L & 7))]);
            float bd = bf2f(sl[(j0 + 3) * 64 + ((((L >> 3) ^ ((j0 + 3) & 7)) << 3) | (L & 7))]);
            o0 += pa * (va + ba);
            o1 += pb * (vbv + bb);
            o2 += pc * (vc + bc);
            o3 += pd * (vd + bd);
        }
        attn_out[(size_t)blk * 256 + w * 64 + L] = f2bf((o0 + o1) + (o2 + o3));

        // ---- write prefetched slab for next item (after current reads) ----
        if (it < 3) write_slab();
    }
}

extern "C" void kernel_launch(void* const* d_in, const int* in_sizes, int n_in,
                              void* d_out, int out_size, void* d_ws, size_t ws_size,
                              hipStream_t stream) {
    const float* x      = (const float*)d_in[0];   // (4096,256)
    const float* bias_f = (const float*)d_in[1];   // (4096,32,256)
    const int*   mask   = (const int*)d_in[2];     // (4096,)
    const float* w_qkv  = (const float*)d_in[3];   // (256,768)
    const float* b_qkv  = (const float*)d_in[4];   // (768,)
    const float* w_proj = (const float*)d_in[5];   // (256,256)
    const float* b_proj = (const float*)d_in[6];   // (256,)
    float* out = (float*)d_out;                    // (4096,256)

    // workspace: q,k,v,attn_out each 4096*256 bf16 (2 MB) = 8.4 MB total
    ushort* qb = (ushort*)d_ws;
    ushort* kb = qb + (size_t)4096 * 256;
    ushort* vb = kb + (size_t)4096 * 256;
    ushort* ao = vb + (size_t)4096 * 256;

    // qkv = x @ w_qkv + b_qkv  ->  bf16 q/k/v   (M=4096, N=768, K=256)
    gemm_fused<64, 64, 2, 2, 0><<<dim3(12, 64), 256, 0, stream>>>(
        x, w_qkv, 768, b_qkv, qb, kb, vb, 256, 768);

    relattn_kernel<<<1024, 256, 0, stream>>>(qb, kb, vb, bias_f, mask, ao);

    // out = attn_out @ w_proj + b_proj   (M=4096, N=256, K=256)
    gemm_fused<32, 64, 1, 4, 1><<<dim3(4, 128), 256, 0, stream>>>(
        ao, w_proj, 256, b_proj, out, nullptr, nullptr, 256, 256);
}

// Round 8
// 74.159 us; speedup vs baseline: 1.3115x; 1.3115x over previous
//
#include <hip/hip_runtime.h>
#include <math.h>

typedef __attribute__((ext_vector_type(8))) short bf16x8;
typedef __attribute__((ext_vector_type(4))) short bf16x4;
typedef __attribute__((ext_vector_type(4))) float f32x4;

__device__ inline ushort f2bf(float f) {
    union { float f; uint u; } v; v.f = f;
    uint u = v.u;
    return (ushort)((u + 0x7fff + ((u >> 16) & 1)) >> 16);   // RNE
}
__device__ inline float bf2f(ushort u) {
    union { uint u; float f; } v; v.u = ((uint)u) << 16; return v.f;
}

// ---------------------------------------------------------------------------
// MFMA bf16 GEMM, converts inputs on the fly.  (unchanged; passed R3-R7)
// ---------------------------------------------------------------------------
template<int BM, int BN, int WGM, int WGN, int MODE>
__global__ __launch_bounds__(WGM * WGN * 64) void gemm_fused(
    const void* __restrict__ Ap, const float* __restrict__ Bw, int ldb,
    const float* __restrict__ bias,
    void* __restrict__ C0, void* __restrict__ C1, void* __restrict__ C2,
    int K, int N)
{
    constexpr int BK = 32;
    constexpr int NT = WGM * WGN * 64;
    constexpr int WM = BM / (WGM * 16);
    constexpr int WN = BN / (WGN * 16);

    __shared__ ushort As[BM * BK];
    __shared__ ushort Bs[BN * BK];

    const int tid = threadIdx.x;
    const int lane = tid & 63, wid = tid >> 6;
    const int wm = wid / WGN, wn = wid % WGN;
    const int row0 = blockIdx.y * BM, col0 = blockIdx.x * BN;
    const int frow = lane & 15, fg = lane >> 4;

    f32x4 acc[WM][WN] = {};

    for (int k0 = 0; k0 < K; k0 += BK) {
        if constexpr (MODE == 0) {
            #pragma unroll
            for (int ci = tid; ci < BM * 8; ci += NT) {
                int r = ci >> 3, kq = ci & 7, g = kq >> 1;
                float4 v = *(const float4*)((const float*)Ap + (size_t)(row0 + r) * K + k0 + kq * 4);
                bf16x4 o;
                o[0] = (short)f2bf(v.x); o[1] = (short)f2bf(v.y);
                o[2] = (short)f2bf(v.z); o[3] = (short)f2bf(v.w);
                *(bf16x4*)&As[r * 32 + ((g ^ ((r >> 1) & 3)) << 3) + (kq & 1) * 4] = o;
            }
        } else {
            #pragma unroll
            for (int ci = tid; ci < BM * 4; ci += NT) {
                int r = ci >> 2, g = ci & 3;
                bf16x8 v = *(const bf16x8*)((const ushort*)Ap + (size_t)(row0 + r) * K + k0 + g * 8);
                *(bf16x8*)&As[r * 32 + ((g ^ ((r >> 1) & 3)) << 3)] = v;
            }
        }
        #pragma unroll
        for (int ci = tid; ci < BN * 8; ci += NT) {
            int kk = ci & 31, n4 = ci >> 5;
            float4 v = *(const float4*)&Bw[(size_t)(k0 + kk) * ldb + col0 + n4 * 4];
            float vv[4] = {v.x, v.y, v.z, v.w};
            #pragma unroll
            for (int e = 0; e < 4; ++e) {
                int n = n4 * 4 + e;
                Bs[n * 32 + (((kk >> 3) ^ ((n >> 1) & 3)) << 3) + (kk & 7)] = f2bf(vv[e]);
            }
        }
        __syncthreads();

        bf16x8 af[WM], bfr[WN];
        #pragma unroll
        for (int m = 0; m < WM; ++m) {
            int r = (wm * WM + m) * 16 + frow;
            af[m] = *(const bf16x8*)&As[r * 32 + ((fg ^ ((r >> 1) & 3)) << 3)];
        }
        #pragma unroll
        for (int n = 0; n < WN; ++n) {
            int r = (wn * WN + n) * 16 + frow;
            bfr[n] = *(const bf16x8*)&Bs[r * 32 + ((fg ^ ((r >> 1) & 3)) << 3)];
        }
        #pragma unroll
        for (int m = 0; m < WM; ++m)
            #pragma unroll
            for (int n = 0; n < WN; ++n)
                acc[m][n] = __builtin_amdgcn_mfma_f32_16x16x32_bf16(
                    af[m], bfr[n], acc[m][n], 0, 0, 0);
        __syncthreads();
    }

    #pragma unroll
    for (int n = 0; n < WN; ++n) {
        int gcol = col0 + (wn * WN + n) * 16 + frow;
        float bv = bias[gcol];
        if constexpr (MODE == 0) {
            int b = gcol >> 8, c = gcol & 255;
            ushort* dst = (b == 0) ? (ushort*)C0 : (b == 1) ? (ushort*)C1 : (ushort*)C2;
            #pragma unroll
            for (int m = 0; m < WM; ++m) {
                int grow0 = row0 + (wm * WM + m) * 16 + fg * 4;
                #pragma unroll
                for (int r = 0; r < 4; ++r)
                    dst[(size_t)(grow0 + r) * 256 + c] = f2bf(acc[m][n][r] + bv);
            }
        } else {
            float* dst = (float*)C0;
            #pragma unroll
            for (int m = 0; m < WM; ++m) {
                int grow0 = row0 + (wm * WM + m) * 16 + fg * 4;
                #pragma unroll
                for (int r = 0; r < 4; ++r)
                    dst[(size_t)(grow0 + r) * N + gcol] = acc[m][n][r] + bv;
            }
        }
    }
}

// ---------------------------------------------------------------------------
// Pipelined relational attention, v-in-LDS, k-in-regs, zero per-item global
// latency chain. Grid 1024; block = 4 items (same bt). Per wave (cols
// [w*64,w*64+64)):
//   - v slab staged ONCE per block into LDS (coalesced, linear, 16 KB)
//   - k fragments in registers (broadcast loads, once per block)
//   - bias: double-buffered per-wave LDS slabs (2 x 4 KB), register prefetch
//     issued one item ahead (T14) -> HBM burst in flight under compute
//   - only per-item globals: 4 broadcast q loads + 1 coalesced store
// Bias slab layout: [32 rows][64 cols] bf16; 16B chunk cc of row j at slot
// cc^(j&7). Stage write quarter-wave = one row -> conflict-free. PV 2-way.
// ---------------------------------------------------------------------------
__global__ __launch_bounds__(256, 3) void relattn_kernel(
    const ushort* __restrict__ qb, const ushort* __restrict__ kb,
    const ushort* __restrict__ vb, const float* __restrict__ bias,
    const int* __restrict__ mask, ushort* __restrict__ attn_out)
{
    __shared__ ushort vslab[8192];          // [32][256] bf16, linear
    __shared__ ushort slab[4][2][2048];     // per-wave bias dbuf, 4 KB each

    const int b = blockIdx.x;               // 0..1023
    const int item0 = b << 2;
    const int bt = item0 >> 5;              // constant for the 4 items
    const int tid = threadIdx.x;
    const int w = tid >> 6, L = tid & 63;
    const int hw = L >> 5;                  // which of the wave's two heads
    const int h = 2 * w + hw;
    const int jd = L & 31;                  // j in scores, d in PV

    const bool alive = (mask[bt * 32 + jd] != 0);

    // ---- stage v slab once (coalesced 8B/lane), linear layout ----
    const ushort* vsrc = vb + (size_t)bt * 8192;
    #pragma unroll
    for (int itv = 0; itv < 8; ++itv) {
        int idx = (itv * 256 + tid) * 4;
        *(bf16x4*)&vslab[idx] = *(const bf16x4*)(vsrc + idx);
    }

    // ---- k fragments: once per block (broadcast within 32-lane groups) ----
    const ushort* krow = kb + (size_t)(bt * 32 + jd) * 256 + h * 32;
    bf16x8 k8[4];
    #pragma unroll
    for (int t = 0; t < 4; ++t) k8[t] = *(const bf16x8*)(krow + t * 8);

    // ---- bias prefetch mapping: g=0..7 -> row j=g*4+(L>>4), f32x4 at col (L&15)*4 ----
    const float* bbase = bias + (size_t)item0 * 8192 + w * 64;
    const int srow = L >> 4, sc = L & 15;
    ushort* myslab0 = slab[w][0];
    ushort* myslab1 = slab[w][1];

    float4 pref[8];
    #pragma unroll
    for (int g = 0; g < 8; ++g)
        pref[g] = *(const float4*)(bbase + (size_t)(g * 4 + srow) * 256 + sc * 4);

    auto write_slab = [&](ushort* sl) {
        #pragma unroll
        for (int g = 0; g < 8; ++g) {
            int j = g * 4 + srow;
            int cc = sc >> 1, half = sc & 1;
            bf16x4 o;
            o[0] = (short)f2bf(pref[g].x); o[1] = (short)f2bf(pref[g].y);
            o[2] = (short)f2bf(pref[g].z); o[3] = (short)f2bf(pref[g].w);
            *(bf16x4*)&sl[j * 64 + ((cc ^ (j & 7)) << 3) + half * 4] = o;
        }
    };

    __syncthreads();            // v slab ready (once per block)
    write_slab(myslab0);

    #pragma unroll
    for (int it = 0; it < 4; ++it) {
        const int blk = item0 + it;
        ushort* cur = (it & 1) ? myslab1 : myslab0;
        ushort* nxt = (it & 1) ? myslab0 : myslab1;

        // ---- issue next item's bias burst (stays in flight under compute) ----
        if (it < 3) {
            const float* nb = bbase + (size_t)(it + 1) * 8192;
            #pragma unroll
            for (int g = 0; g < 8; ++g)
                pref[g] = *(const float4*)(nb + (size_t)(g * 4 + srow) * 256 + sc * 4);
        }

        // ---- scores: thread (h, j=jd) ----
        const ushort* qrow = qb + (size_t)blk * 256 + h * 32;
        float s = 0.f;
        #pragma unroll
        for (int t = 0; t < 4; ++t) {
            bf16x8 q8 = *(const bf16x8*)(qrow + t * 8);
            int cc = hw * 4 + t;
            bf16x8 b8 = *(const bf16x8*)&cur[jd * 64 + ((cc ^ (jd & 7)) << 3)];
            #pragma unroll
            for (int e = 0; e < 8; ++e)
                s += bf2f((ushort)q8[e]) * (bf2f((ushort)k8[t][e]) + bf2f((ushort)b8[e]));
        }
        s *= 0.17677669529663687f;  // 1/sqrt(32)
        s = alive ? s : -__builtin_inff();

        // softmax within the 32-lane j-group
        float m = s;
        #pragma unroll
        for (int off = 16; off; off >>= 1) m = fmaxf(m, __shfl_xor(m, off));
        const bool dead = (m == -__builtin_inff());
        float p = alive ? __expf(s - m) : 0.f;
        float l = p;
        #pragma unroll
        for (int off = 16; off; off >>= 1) l += __shfl_xor(l, off);
        float pn = dead ? 0.f : p / l;

        // ---- PV: thread (h, d); v from LDS, bias from slab, p via shfl ----
        const int half32 = L & 32;
        const int col = w * 64 + L;
        float o0 = 0.f, o1 = 0.f, o2 = 0.f, o3 = 0.f;
        #pragma unroll
        for (int jq = 0; jq < 8; ++jq) {
            int j0 = jq * 4;
            float pa = __shfl(pn, half32 | (j0 + 0));
            float pb = __shfl(pn, half32 | (j0 + 1));
            float pc = __shfl(pn, half32 | (j0 + 2));
            float pd = __shfl(pn, half32 | (j0 + 3));
            float va = bf2f(vslab[(j0 + 0) * 256 + col]);
            float vbv = bf2f(vslab[(j0 + 1) * 256 + col]);
            float vc = bf2f(vslab[(j0 + 2) * 256 + col]);
            float vd = bf2f(vslab[(j0 + 3) * 256 + col]);
            float ba = bf2f(cur[(j0 + 0) * 64 + ((((L >> 3) ^ ((j0 + 0) & 7)) << 3) | (L & 7))]);
            float bb = bf2f(cur[(j0 + 1) * 64 + ((((L >> 3) ^ ((j0 + 1) & 7)) << 3) | (L & 7))]);
            float bc = bf2f(cur[(j0 + 2) * 64 + ((((L >> 3) ^ ((j0 + 2) & 7)) << 3) | (L & 7))]);
            float bd = bf2f(cur[(j0 + 3) * 64 + ((((L >> 3) ^ ((j0 + 3) & 7)) << 3) | (L & 7))]);
            o0 += pa * (va + ba);
            o1 += pb * (vbv + bb);
            o2 += pc * (vc + bc);
            o3 += pd * (vd + bd);
        }
        attn_out[(size_t)blk * 256 + w * 64 + L] = f2bf((o0 + o1) + (o2 + o3));

        // ---- write prefetched slab for next item ----
        if (it < 3) write_slab(nxt);
    }
}

extern "C" void kernel_launch(void* const* d_in, const int* in_sizes, int n_in,
                              void* d_out, int out_size, void* d_ws, size_t ws_size,
                              hipStream_t stream) {
    const float* x      = (const float*)d_in[0];   // (4096,256)
    const float* bias_f = (const float*)d_in[1];   // (4096,32,256)
    const int*   mask   = (const int*)d_in[2];     // (4096,)
    const float* w_qkv  = (const float*)d_in[3];   // (256,768)
    const float* b_qkv  = (const float*)d_in[4];   // (768,)
    const float* w_proj = (const float*)d_in[5];   // (256,256)
    const float* b_proj = (const float*)d_in[6];   // (256,)
    float* out = (float*)d_out;                    // (4096,256)

    // workspace: q,k,v,attn_out each 4096*256 bf16 (2 MB) = 8.4 MB total
    ushort* qb = (ushort*)d_ws;
    ushort* kb = qb + (size_t)4096 * 256;
    ushort* vb = kb + (size_t)4096 * 256;
    ushort* ao = vb + (size_t)4096 * 256;

    // qkv = x @ w_qkv + b_qkv  ->  bf16 q/k/v   (M=4096, N=768, K=256)
    gemm_fused<64, 64, 2, 2, 0><<<dim3(12, 64), 256, 0, stream>>>(
        x, w_qkv, 768, b_qkv, qb, kb, vb, 256, 768);

    relattn_kernel<<<1024, 256, 0, stream>>>(qb, kb, vb, bias_f, mask, ao);

    // out = attn_out @ w_proj + b_proj   (M=4096, N=256, K=256)
    gemm_fused<32, 64, 1, 4, 1><<<dim3(4, 128), 256, 0, stream>>>(
        ao, w_proj, 256, b_proj, out, nullptr, nullptr, 256, 256);
}